// Round 1
// baseline (309.593 us; speedup 1.0000x reference)
//
#include <hip/hip_runtime.h>
#include <math.h>

// Exact-equivalent computation of the reference:
//   - LayerNorm over a size-1 axis is identically its bias (mean(x)=x, var=0),
//     so the constraint path is data-independent: h_ln = cons_ln_b[0] for all nodes.
//   - The 2-layer MLP then yields ONE 16-vector shared by every node.
//   - sort-pool over identical rows -> K identical rows; final linear + sigmoid
//     -> one scalar replicated over all n_graphs outputs.
//   - Edge / variable embeddings in the reference are dead (del e, v).
//
// So: compute the scalar from the weights, broadcast-write n_graphs floats.

__global__ __launch_bounds__(256) void gnn_const_head_kernel(
    const float* __restrict__ cons_ln_b,   // [1]
    const float* __restrict__ cons_w1,     // [16,1]
    const float* __restrict__ cons_b1,     // [16]
    const float* __restrict__ cons_w2,     // [16,16] row-major
    const float* __restrict__ cons_b2,     // [16]
    const float* __restrict__ final_w,     // [1, 256] = [k=16][emb=16]
    const float* __restrict__ final_b,     // [1]
    float* __restrict__ out,               // [n_graphs]
    int n_graphs)
{
    __shared__ float s_val;
    if (threadIdx.x == 0) {
        const float b = cons_ln_b[0];
        // h1 = relu(b * w1 + b1)
        float h1[16];
#pragma unroll
        for (int j = 0; j < 16; ++j) {
            float v = fmaf(b, cons_w1[j], cons_b1[j]);
            h1[j] = v > 0.f ? v : 0.f;
        }
        // s = final_b + sum_e relu(h1 . w2_row_e + b2_e) * (sum_k final_w[k*16+e])
        float s = final_b[0];
#pragma unroll
        for (int e = 0; e < 16; ++e) {
            float acc = cons_b2[e];
#pragma unroll
            for (int i = 0; i < 16; ++i)
                acc = fmaf(h1[i], cons_w2[e * 16 + i], acc);
            const float h2 = acc > 0.f ? acc : 0.f;
            float fw = 0.f;
#pragma unroll
            for (int k = 0; k < 16; ++k)
                fw += final_w[k * 16 + e];
            s = fmaf(h2, fw, s);
        }
        s_val = 1.0f / (1.0f + expf(-s));
    }
    __syncthreads();

    const float v = s_val;
    const int tid = blockIdx.x * blockDim.x + threadIdx.x;
    const int i4 = tid * 4;
    if (i4 + 3 < n_graphs) {
        *reinterpret_cast<float4*>(out + i4) = make_float4(v, v, v, v);
    } else if (i4 < n_graphs) {
        for (int i = i4; i < n_graphs; ++i) out[i] = v;
    }
}

extern "C" void kernel_launch(void* const* d_in, const int* in_sizes, int n_in,
                              void* d_out, int out_size, void* d_ws, size_t ws_size,
                              hipStream_t stream) {
    // setup_inputs() dict order:
    //  0 constraint_features  1 edge_indices  2 edge_features  3 variable_features
    //  4 batch  5 ptr
    //  6 cons_ln_w  7 cons_ln_b  8 cons_w1  9 cons_b1  10 cons_w2  11 cons_b2
    // 12 edge_ln_w 13 edge_ln_b
    // 14 var_ln_w 15 var_ln_b 16 var_w1 17 var_b1 18 var_w2 19 var_b2
    // 20 final_w  21 final_b
    const float* cons_ln_b = (const float*)d_in[7];
    const float* cons_w1   = (const float*)d_in[8];
    const float* cons_b1   = (const float*)d_in[9];
    const float* cons_w2   = (const float*)d_in[10];
    const float* cons_b2   = (const float*)d_in[11];
    const float* final_w   = (const float*)d_in[20];
    const float* final_b   = (const float*)d_in[21];

    const int n_graphs = in_sizes[5] - 1;   // ptr has B+1 entries
    float* out = (float*)d_out;

    const int threads = 256;
    const int elems_per_block = threads * 4;
    const int blocks = (n_graphs + elems_per_block - 1) / elems_per_block;

    gnn_const_head_kernel<<<blocks, threads, 0, stream>>>(
        cons_ln_b, cons_w1, cons_b1, cons_w2, cons_b2,
        final_w, final_b, out, n_graphs);
}